// Round 1
// baseline (90.404 us; speedup 1.0000x reference)
//
#include <hip/hip_runtime.h>

// Pixel-shuffle r=4: out[b, c, h*4+i, w*4+j] = in[b, c*16 + i*4 + j, h, w]
// B=32, C=400 (c_out=25), H=W=64. fp32. Pure permute, memory-bound.
//
// Thread t handles 16 contiguous output floats (one 64B chunk):
//   w4 = t & 15        -> output cols [16*w4, 16*w4+16) of row oh
//   oh = (t>>4) & 255  -> h = oh>>2, i = oh&3
//   (t>>12)            -> b*25 + c
// Loads: 4x float4 from channels j=0..3 at w = 4*w4..4*w4+3 (16B aligned,
// wave-coalesced into contiguous 256B row segments). 4x4 register transpose,
// then 4x float4 contiguous stores.

__global__ __launch_bounds__(256) void recon_ps4_kernel(
    const float* __restrict__ in, float* __restrict__ out, int total16)
{
    int t = blockIdx.x * blockDim.x + threadIdx.x;
    if (t >= total16) return;

    const int w4   = t & 15;          // w block index, w = 4*w4 + k
    const int tmp  = t >> 4;
    const int oh   = tmp & 255;       // output row within (b,c) image
    const int bc   = tmp >> 8;        // b*25 + c, range [0, 800)
    const int c    = bc % 25;
    const int b    = bc / 25;
    const int h    = oh >> 2;
    const int i    = oh & 3;

    // base input element offset for j=0 channel
    const int ch0  = b * 400 + c * 16 + i * 4;          // channel index, j=0
    const int base = ch0 * 4096 + h * 64 + w4 * 4;      // element offset

    const float4 v0 = *reinterpret_cast<const float4*>(in + base);
    const float4 v1 = *reinterpret_cast<const float4*>(in + base + 4096);
    const float4 v2 = *reinterpret_cast<const float4*>(in + base + 8192);
    const float4 v3 = *reinterpret_cast<const float4*>(in + base + 12288);

    float4* o = reinterpret_cast<float4*>(out + (size_t)t * 16);
    o[0] = make_float4(v0.x, v1.x, v2.x, v3.x);
    o[1] = make_float4(v0.y, v1.y, v2.y, v3.y);
    o[2] = make_float4(v0.z, v1.z, v2.z, v3.z);
    o[3] = make_float4(v0.w, v1.w, v2.w, v3.w);
}

extern "C" void kernel_launch(void* const* d_in, const int* in_sizes, int n_in,
                              void* d_out, int out_size, void* d_ws, size_t ws_size,
                              hipStream_t stream) {
    const float* in = (const float*)d_in[0];
    float* out = (float*)d_out;

    // total output elements = 32*25*256*256 = 52,428,800; /16 per thread
    const int total16 = out_size / 16;                 // 3,276,800
    const int block = 256;
    const int grid = (total16 + block - 1) / block;    // 12,800 blocks

    recon_ps4_kernel<<<grid, block, 0, stream>>>(in, out, total16);
}

// Round 2
// 78.904 us; speedup vs baseline: 1.1457x; 1.1457x over previous
//
#include <hip/hip_runtime.h>

// Pixel-shuffle r=4: out[b, c, 4h+i, 4w+j] = in[b, c*16 + i*4 + j, h, w]
// B=32, c_out=25, H=W=64, fp32. Pure permute, memory-bound.
//
// Block (256 thr) handles one (b, c, h4): 16 channels x 4 h-rows x 64 w.
//   Input : 16 chunks of 1 KB (contiguous per channel)  -> float4 loads,
//           each instr = 4x 256 B contiguous bursts.
//   Output: 16 KB contiguous (rows oh = 16*h4 .. 16*h4+15) -> float4 stores,
//           each instr = 1 KB contiguous (wave-coalesced).
// LDS[4][64][17] (ch padded 16->17): write scalar (2-way bank alias, free),
// read ds_read_b128 at [hh][w][i*4..i*4+3] (2-way alias, free).

#define CH_PAD 17

__global__ __launch_bounds__(256) void recon_ps4_lds_kernel(
    const float* __restrict__ in, float* __restrict__ out)
{
    __shared__ float lds[4 * 64 * CH_PAD];

    const int blk = blockIdx.x;            // b*400 + c*16 + h4 packing: blk = (b*25+c)*16 + h4
    const int h4  = blk & 15;
    const int bc  = blk >> 4;              // b*25 + c, [0, 800)

    const int td  = threadIdx.x;
    const int ch  = td >> 4;               // 0..15  (local channel)
    const int l16 = td & 15;               // 0..15  (w quad index)

    // ---- global -> registers (float4 x4) ----
    // input element offset: (b*400 + c*16 + ch)*4096 + (h4*4+hh)*64 + w
    const float* src = in + ((size_t)(bc * 16 + ch) * 4096 + (size_t)h4 * 256 + l16 * 4);
    float4 v0 = *reinterpret_cast<const float4*>(src);
    float4 v1 = *reinterpret_cast<const float4*>(src + 64);
    float4 v2 = *reinterpret_cast<const float4*>(src + 128);
    float4 v3 = *reinterpret_cast<const float4*>(src + 192);

    // ---- registers -> LDS, layout [hh][w][ch] ----
    const int w0 = l16 * 4;
    float* p0 = lds + (0 * 64 + w0) * CH_PAD + ch;
    float* p1 = lds + (1 * 64 + w0) * CH_PAD + ch;
    float* p2 = lds + (2 * 64 + w0) * CH_PAD + ch;
    float* p3 = lds + (3 * 64 + w0) * CH_PAD + ch;
    p0[0] = v0.x; p0[CH_PAD] = v0.y; p0[2*CH_PAD] = v0.z; p0[3*CH_PAD] = v0.w;
    p1[0] = v1.x; p1[CH_PAD] = v1.y; p1[2*CH_PAD] = v1.z; p1[3*CH_PAD] = v1.w;
    p2[0] = v2.x; p2[CH_PAD] = v2.y; p2[2*CH_PAD] = v2.z; p2[3*CH_PAD] = v2.w;
    p3[0] = v3.x; p3[CH_PAD] = v3.y; p3[2*CH_PAD] = v3.z; p3[3*CH_PAD] = v3.w;

    __syncthreads();

    // ---- LDS -> registers (b128), -> global contiguous ----
    // output chunk base: (b*25+c)*65536 + 16*h4*256
    float* dst = out + ((size_t)bc * 65536 + (size_t)h4 * 4096);
    const int i  = td >> 6;                // wave id = output sub-row i
    const int w  = td & 63;                // lane    = w

    #pragma unroll
    for (int q = 0; q < 4; ++q) {
        // oh_local = q*4 + i  -> hh = q, row i; read lds[q][w][i*4 + 0..3]
        float4 r = *reinterpret_cast<const float4*>(lds + (q * 64 + w) * CH_PAD + i * 4);
        // out offset: oh_local*256 + w*4  == q*1024 + i*256 + w*4 == q*1024 + td*4
        *reinterpret_cast<float4*>(dst + q * 1024 + td * 4) = r;
    }
}

extern "C" void kernel_launch(void* const* d_in, const int* in_sizes, int n_in,
                              void* d_out, int out_size, void* d_ws, size_t ws_size,
                              hipStream_t stream) {
    const float* in = (const float*)d_in[0];
    float* out = (float*)d_out;

    // grid = B * c_out * (H/4) = 32 * 25 * 16 = 12800 blocks
    recon_ps4_lds_kernel<<<12800, 256, 0, stream>>>(in, out);
}